// Round 13
// baseline (480.385 us; speedup 1.0000x reference)
//
#include <hip/hip_runtime.h>
#include <cstddef>
#include <cstdint>

#define Bc 4
#define Nc 1024
#define Cc 768
#define Hc 12
#define Dc 64
#define BHc 48
#define QKV_ELEMS ((size_t)Bc * Nc * Cc)   // 3145728

typedef __attribute__((ext_vector_type(4))) unsigned int u32x4;
typedef __attribute__((ext_vector_type(2))) unsigned int u32x2;
typedef __attribute__((ext_vector_type(8))) short s16x8;
typedef __attribute__((ext_vector_type(8))) _Float16 h16x8;
typedef __attribute__((ext_vector_type(4))) _Float16 h16x4;
typedef __attribute__((ext_vector_type(4))) float fx4;
typedef __attribute__((ext_vector_type(2))) float fx2;

union Frag { u32x4 u; s16x8 s; h16x8 f16; unsigned short h[8]; };
union H4b { u32x2 d; h16x4 h4; };

__device__ inline unsigned short f2bf(float x) {
    union { float f; uint32_t u; } c; c.f = x;
    return (unsigned short)((c.u + 0x7FFFu + ((c.u >> 16) & 1u)) >> 16);
}
__device__ inline float bf2f(unsigned short b) {
    union { uint32_t u; float f; } c; c.u = ((uint32_t)b) << 16;
    return c.f;
}
__device__ inline void split8(const float* v, u32x4& hi, u32x4& lo) {
    Frag fh, fl;
    #pragma unroll
    for (int e = 0; e < 8; ++e) {
        const unsigned short hb = f2bf(v[e]);
        fh.h[e] = hb;
        fl.h[e] = f2bf(v[e] - bf2f(hb));
    }
    hi = fh.u; lo = fl.u;
}
__device__ inline void split8h(const float* v, u32x4& hi, u32x4& lo) {
    Frag fh, fl;
    #pragma unroll
    for (int e = 0; e < 8; ++e) {
        const _Float16 hb = (_Float16)v[e];
        fh.f16[e] = hb;
        fl.f16[e] = (_Float16)(v[e] - (float)hb);
    }
    hi = fh.u; lo = fl.u;
}

// ---------------------------------------------------------------------------
// prep_w: Wt_hi/lo[mat][n][k] = split(W[k][n])  (bf16 hi/lo)
// ---------------------------------------------------------------------------
__global__ __launch_bounds__(256) void prep_w_kernel(
    const float* __restrict__ Wq, const float* __restrict__ Wk,
    const float* __restrict__ Wv, const float* __restrict__ Wo,
    unsigned short* __restrict__ Thi, unsigned short* __restrict__ Tlo)
{
    __shared__ float scr[64 * 65];
    const int mat = blockIdx.z;
    const float* W = (mat == 0) ? Wq : (mat == 1) ? Wk : (mat == 2) ? Wv : Wo;
    const int k0 = blockIdx.y * 64, n0 = blockIdx.x * 64;
    const int tid = threadIdx.x;

    #pragma unroll
    for (int it = 0; it < 4; ++it) {
        const int lin = tid + it * 256;
        const int r = lin >> 4, c4 = (lin & 15) << 2;
        const fx4 v = *(const fx4*)&W[(size_t)(k0 + r) * 768 + n0 + c4];
        scr[r * 65 + c4 + 0] = v[0]; scr[r * 65 + c4 + 1] = v[1];
        scr[r * 65 + c4 + 2] = v[2]; scr[r * 65 + c4 + 3] = v[3];
    }
    __syncthreads();
    unsigned short* th = Thi + (size_t)mat * 768 * 768;
    unsigned short* tl = Tlo + (size_t)mat * 768 * 768;
    #pragma unroll
    for (int it = 0; it < 16; ++it) {
        const int lin = tid + it * 256;
        const int n = lin >> 6, kq = lin & 63;
        const float val = scr[kq * 65 + n];
        const size_t o = (size_t)(n0 + n) * 768 + k0 + kq;
        const unsigned short hb = f2bf(val);
        th[o] = hb;
        tl[o] = f2bf(val - bf2f(hb));
    }
}

// ---------------------------------------------------------------------------
// prep_tables: PL (alpha,beta) per (segment, h) + 2048-bin u8 idx LUT.
// ---------------------------------------------------------------------------
__global__ __launch_bounds__(256) void prep_tables_kernel(
    const float* __restrict__ Wd1, const float* __restrict__ bd1,
    const float* __restrict__ Wd2, const float* __restrict__ bd2,
    float* __restrict__ abPack, unsigned char* __restrict__ lut)
{
    __shared__ float w1s[16], b1s[16], kn[16];
    __shared__ int rank[16];
    const int tid = threadIdx.x;
    if (tid < 16) {
        const float w1 = Wd1[tid], b1 = bd1[tid];
        w1s[tid] = w1; b1s[tid] = b1;
        kn[tid] = (w1 != 0.0f) ? (-b1 / w1) : INFINITY;
    }
    __syncthreads();
    if (tid < 16) {
        int rk = 0;
        for (int u = 0; u < 16; ++u) {
            const float ku = kn[u], km = kn[tid];
            if (ku < km || (ku == km && u < tid)) ++rk;
        }
        rank[tid] = rk;
    }
    __syncthreads();
    if (tid < 17 * 12) {
        const int s = tid / 12, h = tid % 12;
        float a = 0.0f, be = bd2[h];
        for (int u = 0; u < 16; ++u) {
            const float w1 = w1s[u], b1 = b1s[u];
            bool act;
            if (w1 > 0.0f)      act = (rank[u] < s);
            else if (w1 < 0.0f) act = (rank[u] >= s);
            else                act = (b1 > 0.0f);
            if (act) {
                const float w2 = Wd2[u * 12 + h];
                a  += w2 * w1;
                be += w2 * b1;
            }
        }
        abPack[tid * 2 + 0] = a;
        abPack[tid * 2 + 1] = be;
    }
    for (int b = tid; b < 2048; b += 256) {
        const float rep = (b + 0.5f) * (1.41422f / 2048.0f);
        int cnt = 0;
        for (int t = 0; t < 16; ++t) cnt += (rep > kn[t]) ? 1 : 0;
        lut[b] = (unsigned char)cnt;
    }
}

// ---------------------------------------------------------------------------
// split_x: x fp32 -> xhi/xlo bf16 row-major
// ---------------------------------------------------------------------------
__global__ __launch_bounds__(256) void split_x_kernel(
    const float* __restrict__ x, unsigned short* __restrict__ xhi,
    unsigned short* __restrict__ xlo)
{
    const size_t t = (size_t)blockIdx.x * 256 + threadIdx.x;
    float vv[8];
    const fx4 a = *(const fx4*)&x[t * 8];
    const fx4 b = *(const fx4*)&x[t * 8 + 4];
    vv[0]=a[0]; vv[1]=a[1]; vv[2]=a[2]; vv[3]=a[3];
    vv[4]=b[0]; vv[5]=b[1]; vv[6]=b[2]; vv[7]=b[3];
    u32x4 hi, lo; split8(vv, hi, lo);
    *(u32x4*)&xhi[t * 8] = hi;
    *(u32x4*)&xlo[t * 8] = lo;
}

// ---------------------------------------------------------------------------
// gemm_mfma (r10 template): OMODE 0 q/k bf16 hi/lo heads; 1 vT f16 hi/lo.
// ---------------------------------------------------------------------------
struct SmemG { u32x4 ah[512]; u32x4 al[512]; u32x4 bh[512]; u32x4 bl[512]; };
struct SmemT { float scr[64 * 68]; };
union SmemU { SmemG g; SmemT t; };

template<int OMODE>
__global__ __launch_bounds__(256) void gemm_mfma_kernel(
    const unsigned short* __restrict__ Ahi, const unsigned short* __restrict__ Alo,
    const unsigned short* __restrict__ Bhi, const unsigned short* __restrict__ Blo,
    const float* __restrict__ bias,
    unsigned short* __restrict__ Ohi, unsigned short* __restrict__ Olo)
{
    __shared__ SmemU sm;
    const int tid = threadIdx.x;
    const int w = tid >> 6, L = tid & 63;
    const int Lr = L & 15, Lg = L >> 4;
    const int m0 = blockIdx.y * 64, n0 = blockIdx.x * 64;

    fx4 acc[2][2] = {};

    for (int kk = 0; kk < 768; kk += 64) {
        #pragma unroll
        for (int it = 0; it < 2; ++it) {
            const int slot = tid + it * 256;
            const int s = slot >> 6, l = slot & 63;
            const int row = m0 + ((s >> 1) << 4) + (l & 15);
            const int kb = kk + ((s & 1) << 5) + ((l >> 4) << 3);
            sm.g.ah[slot] = *(const u32x4*)&Ahi[(size_t)row * 768 + kb];
            sm.g.al[slot] = *(const u32x4*)&Alo[(size_t)row * 768 + kb];
            const int col = n0 + ((s >> 1) << 4) + (l & 15);
            sm.g.bh[slot] = *(const u32x4*)&Bhi[(size_t)col * 768 + kb];
            sm.g.bl[slot] = *(const u32x4*)&Blo[(size_t)col * 768 + kb];
        }
        __syncthreads();
        #pragma unroll
        for (int kc = 0; kc < 2; ++kc) {
            Frag ah[2], al[2], bh[2], bl[2];
            #pragma unroll
            for (int mm = 0; mm < 2; ++mm) {
                const int rg = (w >> 1) * 2 + mm;
                ah[mm].u = sm.g.ah[(rg * 2 + kc) * 64 + L];
                al[mm].u = sm.g.al[(rg * 2 + kc) * 64 + L];
            }
            #pragma unroll
            for (int nn = 0; nn < 2; ++nn) {
                const int cg = (w & 1) * 2 + nn;
                bh[nn].u = sm.g.bh[(cg * 2 + kc) * 64 + L];
                bl[nn].u = sm.g.bl[(cg * 2 + kc) * 64 + L];
            }
            #pragma unroll
            for (int mm = 0; mm < 2; ++mm)
                #pragma unroll
                for (int nn = 0; nn < 2; ++nn) {
                    acc[mm][nn] = __builtin_amdgcn_mfma_f32_16x16x32_bf16(ah[mm].s, bh[nn].s, acc[mm][nn], 0, 0, 0);
                    acc[mm][nn] = __builtin_amdgcn_mfma_f32_16x16x32_bf16(ah[mm].s, bl[nn].s, acc[mm][nn], 0, 0, 0);
                    acc[mm][nn] = __builtin_amdgcn_mfma_f32_16x16x32_bf16(al[mm].s, bh[nn].s, acc[mm][nn], 0, 0, 0);
                }
        }
        __syncthreads();
    }

    #pragma unroll
    for (int mm = 0; mm < 2; ++mm) {
        const int rl = (w >> 1) * 32 + mm * 16 + Lg * 4;
        #pragma unroll
        for (int nn = 0; nn < 2; ++nn) {
            const int cl = (w & 1) * 32 + nn * 16 + Lr;
            const float bs = bias[n0 + cl];
            #pragma unroll
            for (int r = 0; r < 4; ++r)
                sm.t.scr[(rl + r) * 68 + cl] = acc[mm][nn][r] + bs;
        }
    }
    __syncthreads();

    if (OMODE == 0) {
        const int h = n0 >> 6;
        #pragma unroll
        for (int it = 0; it < 2; ++it) {
            const int t = tid + it * 256;
            const int r = t >> 3, d0 = (t & 7) << 3;
            float vv[8];
            #pragma unroll
            for (int e = 0; e < 8; ++e) vv[e] = sm.t.scr[r * 68 + d0 + e];
            u32x4 hi, lo; split8(vv, hi, lo);
            const int rg = m0 + r, b = rg >> 10, nloc = rg & 1023;
            const size_t o = (((size_t)(b * Hc + h) * Nc + nloc) << 6) + d0;
            *(u32x4*)&Ohi[o] = hi;
            *(u32x4*)&Olo[o] = lo;
        }
    } else {
        const int b = m0 >> 10, h = n0 >> 6, nbase = m0 & 1023;
        #pragma unroll
        for (int it = 0; it < 2; ++it) {
            const int t = tid + it * 256;
            const int dd = t >> 3, j0 = (t & 7) << 3;
            float vv[8];
            #pragma unroll
            for (int e = 0; e < 8; ++e) vv[e] = sm.t.scr[(j0 + e) * 68 + dd];
            u32x4 hi, lo; split8h(vv, hi, lo);   // f16 hi/lo for PV
            const size_t o = (size_t)((b * Hc + h) * Dc + dd) * Nc + nbase + j0;
            *(u32x4*)&Ohi[o] = hi;
            *(u32x4*)&Olo[o] = lo;
        }
    }
}

// ---------------------------------------------------------------------------
// gemm_out: out = (P0*w0 + P1*w1)[4096x768] @ Wo^T + bo, fp32 out.
// ---------------------------------------------------------------------------
__global__ __launch_bounds__(256) void gemm_out_kernel(
    const float* __restrict__ P0, const float* __restrict__ P1,
    const float* __restrict__ wcomb,
    const unsigned short* __restrict__ Bhi, const unsigned short* __restrict__ Blo,
    const float* __restrict__ bias,
    float* __restrict__ outF)
{
    __shared__ SmemU sm;
    const int tid = threadIdx.x;
    const int w = tid >> 6, L = tid & 63;
    const int Lr = L & 15, Lg = L >> 4;
    const int m0 = blockIdx.y * 64, n0 = blockIdx.x * 64;

    fx4 acc[2][2] = {};

    for (int kk = 0; kk < 768; kk += 64) {
        #pragma unroll
        for (int it = 0; it < 2; ++it) {
            const int slot = tid + it * 256;
            const int s = slot >> 6, l = slot & 63;
            const int row = m0 + ((s >> 1) << 4) + (l & 15);
            const int kb = kk + ((s & 1) << 5) + ((l >> 4) << 3);
            {
                const fx4 a0 = *(const fx4*)&P0[(size_t)row * 768 + kb];
                const fx4 a1 = *(const fx4*)&P0[(size_t)row * 768 + kb + 4];
                const fx4 c0 = *(const fx4*)&P1[(size_t)row * 768 + kb];
                const fx4 c1 = *(const fx4*)&P1[(size_t)row * 768 + kb + 4];
                const int hh = kb >> 6, bb = row >> 10, nn = row & 1023;
                const fx2 wc = *(const fx2*)&wcomb[((size_t)(bb * Hc + hh) * Nc + nn) * 2];
                float vv[8];
                vv[0]=a0[0]*wc[0]+c0[0]*wc[1]; vv[1]=a0[1]*wc[0]+c0[1]*wc[1];
                vv[2]=a0[2]*wc[0]+c0[2]*wc[1]; vv[3]=a0[3]*wc[0]+c0[3]*wc[1];
                vv[4]=a1[0]*wc[0]+c1[0]*wc[1]; vv[5]=a1[1]*wc[0]+c1[1]*wc[1];
                vv[6]=a1[2]*wc[0]+c1[2]*wc[1]; vv[7]=a1[3]*wc[0]+c1[3]*wc[1];
                u32x4 hi, lo; split8(vv, hi, lo);
                sm.g.ah[slot] = hi;
                sm.g.al[slot] = lo;
            }
            const int col = n0 + ((s >> 1) << 4) + (l & 15);
            sm.g.bh[slot] = *(const u32x4*)&Bhi[(size_t)col * 768 + kb];
            sm.g.bl[slot] = *(const u32x4*)&Blo[(size_t)col * 768 + kb];
        }
        __syncthreads();
        #pragma unroll
        for (int kc = 0; kc < 2; ++kc) {
            Frag ah[2], al[2], bh[2], bl[2];
            #pragma unroll
            for (int mm = 0; mm < 2; ++mm) {
                const int rg = (w >> 1) * 2 + mm;
                ah[mm].u = sm.g.ah[(rg * 2 + kc) * 64 + L];
                al[mm].u = sm.g.al[(rg * 2 + kc) * 64 + L];
            }
            #pragma unroll
            for (int nn = 0; nn < 2; ++nn) {
                const int cg = (w & 1) * 2 + nn;
                bh[nn].u = sm.g.bh[(cg * 2 + kc) * 64 + L];
                bl[nn].u = sm.g.bl[(cg * 2 + kc) * 64 + L];
            }
            #pragma unroll
            for (int mm = 0; mm < 2; ++mm)
                #pragma unroll
                for (int nn = 0; nn < 2; ++nn) {
                    acc[mm][nn] = __builtin_amdgcn_mfma_f32_16x16x32_bf16(ah[mm].s, bh[nn].s, acc[mm][nn], 0, 0, 0);
                    acc[mm][nn] = __builtin_amdgcn_mfma_f32_16x16x32_bf16(ah[mm].s, bl[nn].s, acc[mm][nn], 0, 0, 0);
                    acc[mm][nn] = __builtin_amdgcn_mfma_f32_16x16x32_bf16(al[mm].s, bh[nn].s, acc[mm][nn], 0, 0, 0);
                }
        }
        __syncthreads();
    }

    #pragma unroll
    for (int mm = 0; mm < 2; ++mm) {
        const int rl = (w >> 1) * 32 + mm * 16 + Lg * 4;
        #pragma unroll
        for (int nn = 0; nn < 2; ++nn) {
            const int cl = (w & 1) * 32 + nn * 16 + Lr;
            const float bs = bias[n0 + cl];
            #pragma unroll
            for (int r = 0; r < 4; ++r)
                sm.t.scr[(rl + r) * 68 + cl] = acc[mm][nn][r] + bs;
        }
    }
    __syncthreads();

    #pragma unroll
    for (int it = 0; it < 4; ++it) {
        const int lin = tid + it * 256;
        const int r = lin >> 4, c4 = (lin & 15) << 2;
        const fx4 v = *(const fx4*)&sm.t.scr[r * 68 + c4];
        *(fx4*)&outF[(size_t)(m0 + r) * 768 + n0 + c4] = v;
    }
}

// ---------------------------------------------------------------------------
// attn_flash (r13): r12 j-split halves + 3-term PV (A = f16 hi/lo) so the
// PV A-operand rounding (2^-11) no longer dominates Output-0 error.
// ---------------------------------------------------------------------------
struct VBuf { u32x4 vh[512]; u32x4 vl[512]; };          // 16 KB
union FlashSmem { VBuf vbuf; float scr[64 * 68]; };     // 17.4 KB

__global__ __launch_bounds__(256) void attn_flash_kernel(
    const unsigned short* __restrict__ qhi, const unsigned short* __restrict__ qlo,
    const unsigned short* __restrict__ khi, const unsigned short* __restrict__ klo,
    const unsigned short* __restrict__ vThi, const unsigned short* __restrict__ vTlo,
    const float* __restrict__ coords,
    const float* __restrict__ abPack, const unsigned char* __restrict__ lutg,
    unsigned short* __restrict__ e_ws, float* __restrict__ mT,
    float* __restrict__ mlh, float* __restrict__ Hp)
{
    __shared__ FlashSmem sm;
    __shared__ unsigned char luts[2048];
    __shared__ fx2 abt[17];

    const int tid = threadIdx.x;
    const int w = tid >> 6, L = tid & 63;
    const int Lr = L & 15, Lg = L >> 4;
    const int bh = blockIdx.z, b = bh / Hc, h = bh % Hc;
    const int half = blockIdx.y;
    const int i0 = blockIdx.x * 64;
    const int iloc = w * 16 + Lr;
    const int i = i0 + iloc;
    const int Lg4 = Lg * 4;

    if (tid < 17) abt[tid] = ((const fx2*)abPack)[tid * Hc + h];
    for (int t = tid; t < 512; t += 256)
        ((uint32_t*)luts)[t] = ((const uint32_t*)lutg)[t];

    Frag qh[2], ql[2];
    #pragma unroll
    for (int kc = 0; kc < 2; ++kc) {
        const size_t o = ((size_t)bh * Nc + i) * 64 + kc * 32 + Lg * 8;
        qh[kc].u = *(const u32x4*)&qhi[o];
        ql[kc].u = *(const u32x4*)&qlo[o];
    }
    const fx2 ci = *(const fx2*)&coords[((size_t)b * Nc + i) * 2];
    const fx2* cjall = (const fx2*)coords + (size_t)b * Nc;

    // prologue: stage V(half tile 0) -> vbuf
    #pragma unroll
    for (int it = 0; it < 2; ++it) {
        const int s = tid + it * 256;
        const int l = s & 63;
        const int dd = ((s >> 7) << 4) + (l & 15);
        const int jo = half * 512 + ((s >> 6) & 1) * 32 + ((l >> 4) << 3);
        const size_t off = ((size_t)bh * Dc + dd) * Nc + jo;
        sm.vbuf.vh[s] = *(const u32x4*)&vThi[off];
        sm.vbuf.vl[s] = *(const u32x4*)&vTlo[off];
    }
    __syncthreads();

    fx4 oacc[4] = {};
    float m_r = -INFINITY, l_r = 0.f;

    for (int jt = 0; jt < 8; ++jt) {
        const int jbase = half * 512 + jt * 64;
        const int jglob = half * 8 + jt;

        // prefetch V(jt+1) -> regs
        u32x4 vsh[2], vsl[2];
        if (jt < 7) {
            #pragma unroll
            for (int it = 0; it < 2; ++it) {
                const int s = tid + it * 256;
                const int l = s & 63;
                const int dd = ((s >> 7) << 4) + (l & 15);
                const int jo = jbase + 64 + ((s >> 6) & 1) * 32 + ((l >> 4) << 3);
                const size_t off = ((size_t)bh * Dc + dd) * Nc + jo;
                vsh[it] = *(const u32x4*)&vThi[off];
                vsl[it] = *(const u32x4*)&vTlo[off];
            }
        }

        // QK^T (swapped: A = K rows j, B = Q cols i)
        fx4 acc[4] = {};
        #pragma unroll
        for (int kc = 0; kc < 2; ++kc) {
            Frag kh[4], kl[4];
            #pragma unroll
            for (int cg = 0; cg < 4; ++cg) {
                const size_t o = ((size_t)bh * Nc + jbase + cg * 16 + Lr) * 64 + kc * 32 + Lg * 8;
                kh[cg].u = *(const u32x4*)&khi[o];
                kl[cg].u = *(const u32x4*)&klo[o];
            }
            #pragma unroll
            for (int cg = 0; cg < 4; ++cg) {
                acc[cg] = __builtin_amdgcn_mfma_f32_16x16x32_bf16(kh[cg].s, qh[kc].s, acc[cg], 0, 0, 0);
                acc[cg] = __builtin_amdgcn_mfma_f32_16x16x32_bf16(kl[cg].s, qh[kc].s, acc[cg], 0, 0, 0);
                acc[cg] = __builtin_amdgcn_mfma_f32_16x16x32_bf16(kh[cg].s, ql[kc].s, acc[cg], 0, 0, 0);
            }
        }

        // spatial PL-MLP + combine
        float sv[16];
        #pragma unroll
        for (int cg = 0; cg < 4; ++cg) {
            #pragma unroll
            for (int r = 0; r < 4; ++r) {
                const fx2 cj = cjall[jbase + cg * 16 + Lg4 + r];
                const float dx = ci[0] - cj[0], dy = ci[1] - cj[1];
                const float dist = sqrtf(fmaf(dx, dx, fmaf(dy, dy, 1e-6f)));
                int bin = (int)(dist * (2048.0f / 1.41422f));
                bin = (bin > 2047) ? 2047 : bin;
                const fx2 ab = abt[luts[bin]];
                sv[cg * 4 + r] = fmaf(acc[cg][r], 0.125f, fmaf(ab[0], dist, ab[1]));
            }
        }

        // per-row (Lr) tile max + e + tile sum
        float tm = sv[0];
        #pragma unroll
        for (int e = 1; e < 16; ++e) tm = fmaxf(tm, sv[e]);
        tm = fmaxf(tm, __shfl_xor(tm, 16));
        tm = fmaxf(tm, __shfl_xor(tm, 32));

        float ts = 0.f;
        #pragma unroll
        for (int e = 0; e < 16; ++e) { sv[e] = __expf(sv[e] - tm); ts += sv[e]; }
        ts += __shfl_xor(ts, 16);
        ts += __shfl_xor(ts, 32);

        if (Lg == 0) mT[((size_t)bh * Nc + i) * 16 + jglob] = tm;

        // e_ws store (f16), layout [bh][jglob][kc][i][32j]
        const size_t ebase = ((size_t)(bh * 16 + jglob) * 2) * 32768 + (size_t)i * 32;
        #pragma unroll
        for (int cg = 0; cg < 4; ++cg) {
            H4b pk;
            #pragma unroll
            for (int r = 0; r < 4; ++r) pk.h4[r] = (_Float16)sv[cg * 4 + r];
            *(u32x2*)&e_ws[ebase + (size_t)(cg >> 1) * 32768 + (cg & 1) * 16 + Lg4] = pk.d;
        }

        // online rescale (row stats in lane Lr; acc rows = Lg4+r -> shfl)
        const float mnew = fmaxf(m_r, tm);
        const float facc = __expf(m_r - mnew);
        const float ftile = __expf(tm - mnew);
        l_r = l_r * facc + ts * ftile;
        m_r = mnew;
        #pragma unroll
        for (int r = 0; r < 4; ++r) {
            const float fr = __shfl(facc, Lg4 + r);
            #pragma unroll
            for (int dg = 0; dg < 4; ++dg) oacc[dg][r] *= fr;
        }

        // PV: K=16 f16 MFMA, 3-term (A hi/lo) for ~2^-21 A-side error
        const char* vhB = (const char*)sm.vbuf.vh;
        const char* vlB = (const char*)sm.vbuf.vl;
        #pragma unroll
        for (int cg = 0; cg < 4; ++cg) {
            H4b ah4, al4;
            #pragma unroll
            for (int r = 0; r < 4; ++r) {
                const float a = sv[cg * 4 + r] * ftile;
                const _Float16 ahh = (_Float16)a;
                ah4.h4[r] = ahh;
                al4.h4[r] = (_Float16)(a - (float)ahh);
            }
            const int sub = (cg & 1) * 2 + (Lg >> 1);
            const int kcq = cg >> 1;
            const int low = (Lg & 1) * 8;
            #pragma unroll
            for (int dg = 0; dg < 4; ++dg) {
                const int byteoff = ((dg * 2 + kcq) * 64 + sub * 16 + Lr) * 16 + low;
                H4b bh4, bl4;
                bh4.d = *(const u32x2*)(vhB + byteoff);
                bl4.d = *(const u32x2*)(vlB + byteoff);
                oacc[dg] = __builtin_amdgcn_mfma_f32_16x16x16f16(ah4.h4, bh4.h4, oacc[dg], 0, 0, 0);
                oacc[dg] = __builtin_amdgcn_mfma_f32_16x16x16f16(ah4.h4, bl4.h4, oacc[dg], 0, 0, 0);
                oacc[dg] = __builtin_amdgcn_mfma_f32_16x16x16f16(al4.h4, bh4.h4, oacc[dg], 0, 0, 0);
            }
        }

        __syncthreads();   // all waves done reading vbuf for this jt
        if (jt < 7) {
            #pragma unroll
            for (int it = 0; it < 2; ++it) {
                const int s = tid + it * 256;
                sm.vbuf.vh[s] = vsh[it];
                sm.vbuf.vl[s] = vsl[it];
            }
            __syncthreads();   // V(jt+1) visible
        }
    }

    // per-half stats
    if (Lg == 0) {
        *(fx2*)&mlh[((size_t)bh * Nc + i) * 4 + half * 2] = fx2{m_r, l_r};
    }

    // raw partial PV plane (f32) via scr restage
    #pragma unroll
    for (int dg = 0; dg < 4; ++dg)
        #pragma unroll
        for (int r = 0; r < 4; ++r)
            sm.scr[(w * 16 + Lg4 + r) * 68 + dg * 16 + Lr] = oacc[dg][r];
    __syncthreads();

    float* HpH = Hp + (size_t)half * QKV_ELEMS;
    #pragma unroll
    for (int it = 0; it < 2; ++it) {
        const int lin = tid + it * 256;
        const int row = lin >> 3, d0 = (lin & 7) << 3;
        const fx4 v0 = *(const fx4*)&sm.scr[row * 68 + d0];
        const fx4 v1 = *(const fx4*)&sm.scr[row * 68 + d0 + 4];
        const size_t o = ((size_t)b * Nc + i0 + row) * Cc + h * Dc + d0;
        *(fx4*)&HpH[o] = v0;
        *(fx4*)&HpH[o + 4] = v1;
    }
}

// ---------------------------------------------------------------------------
// norm: combine halves' (m,l); attn = e * exp(m_t - m_row)/l_row; emit wcomb.
// ---------------------------------------------------------------------------
__global__ __launch_bounds__(256) void norm_kernel(
    const unsigned short* __restrict__ e_ws,
    const float* __restrict__ mT, const float* __restrict__ mlh,
    float* __restrict__ attn, float* __restrict__ wcomb)
{
    const size_t t = (size_t)blockIdx.x * 256 + threadIdx.x;   // < 1572864
    const int blk = (int)(t >> 10);
    const int i = (int)(t & 1023);
    const int bh = blk >> 5;
    const int jt = (blk >> 1) & 15;
    const int kc = blk & 1;
    const size_t row = (size_t)bh * Nc + i;

    const fx4 m4 = *(const fx4*)&mlh[row * 4];   // m0,l0,m1,l1
    const float m_row = fmaxf(m4[0], m4[2]);
    const float l_row = m4[1] * __expf(m4[0] - m_row) + m4[3] * __expf(m4[2] - m_row);
    const float il = 1.0f / l_row;
    const float mt = mT[row * 16 + jt];
    const float f = __expf(mt - m_row) * il;

    if (jt == 0 && kc == 0) {
        wcomb[row * 2 + 0] = __expf(m4[0] - m_row) * il;
        wcomb[row * 2 + 1] = __expf(m4[2] - m_row) * il;
    }

    const unsigned short* ep = &e_ws[(size_t)blk * 32768 + (size_t)i * 32];
    float* ap = &attn[row * Nc + jt * 64 + kc * 32];
    #pragma unroll
    for (int c = 0; c < 4; ++c) {
        Frag ev;
        ev.u = *(const u32x4*)&ep[c * 8];
        fx4 o0, o1;
        o0[0] = (float)ev.f16[0] * f; o0[1] = (float)ev.f16[1] * f;
        o0[2] = (float)ev.f16[2] * f; o0[3] = (float)ev.f16[3] * f;
        o1[0] = (float)ev.f16[4] * f; o1[1] = (float)ev.f16[5] * f;
        o1[2] = (float)ev.f16[6] * f; o1[3] = (float)ev.f16[7] * f;
        *(fx4*)&ap[c * 8] = o0;
        *(fx4*)&ap[c * 8 + 4] = o1;
    }
}

// ---------------------------------------------------------------------------
extern "C" void kernel_launch(void* const* d_in, const int* in_sizes, int n_in,
                              void* d_out, int out_size, void* d_ws, size_t ws_size,
                              hipStream_t stream)
{
    (void)in_sizes; (void)n_in; (void)out_size; (void)ws_size;

    const float* x      = (const float*)d_in[0];
    const float* coords = (const float*)d_in[1];
    const float* Wq = (const float*)d_in[2];  const float* bq = (const float*)d_in[3];
    const float* Wk = (const float*)d_in[4];  const float* bk = (const float*)d_in[5];
    const float* Wv = (const float*)d_in[6];  const float* bv = (const float*)d_in[7];
    const float* Wo = (const float*)d_in[8];  const float* bo = (const float*)d_in[9];
    const float* Wd1 = (const float*)d_in[10]; const float* bd1 = (const float*)d_in[11];
    const float* Wd2 = (const float*)d_in[12]; const float* bd2 = (const float*)d_in[13];

    float* out_main = (float*)d_out;            // [B,N,C]
    float* attn     = out_main + QKV_ELEMS;     // [B,H,N,N]

    uint8_t* wsb = (uint8_t*)d_ws;
    const size_t SZ_BF = (size_t)BHc * Nc * Dc * 2;          // 6,291,456 B
    const size_t SZ_W4 = (size_t)4 * 768 * 768 * 2;          // 4,718,592 B
    unsigned short* qhi  = (unsigned short*)(wsb + 0 * SZ_BF);
    unsigned short* qlo  = (unsigned short*)(wsb + 1 * SZ_BF);
    unsigned short* khi  = (unsigned short*)(wsb + 2 * SZ_BF);
    unsigned short* klo  = (unsigned short*)(wsb + 3 * SZ_BF);
    unsigned short* vThi = (unsigned short*)(wsb + 4 * SZ_BF);
    unsigned short* vTlo = (unsigned short*)(wsb + 5 * SZ_BF);
    unsigned short* xhi  = (unsigned short*)(wsb + 6 * SZ_BF);
    unsigned short* xlo  = (unsigned short*)(wsb + 7 * SZ_BF);
    unsigned short* Thi  = (unsigned short*)(wsb + 8 * SZ_BF);
    unsigned short* Tlo  = (unsigned short*)(wsb + 8 * SZ_BF + SZ_W4);
    uint8_t* base8 = wsb + 8 * SZ_BF + 2 * SZ_W4;
    float* abPack = (float*)base8;                            // 408 floats
    unsigned char* lut = (unsigned char*)(base8 + 4096);      // 2048 B
    float* mT    = (float*)(base8 + 8192);                    // 48*1024*16 f32 = 3 MB
    float* mlh   = mT + (size_t)BHc * Nc * 16;                // 48*1024*4 f32
    float* wcomb = mlh + (size_t)BHc * Nc * 4;                // 48*1024*2 f32
    float* Hp    = wcomb + (size_t)BHc * Nc * 2;              // 2 x 12.58 MB f32
    unsigned short* e_ws = (unsigned short*)(Hp + 2 * QKV_ELEMS); // f16 e, 100.7 MB

    prep_w_kernel<<<dim3(12, 12, 4), 256, 0, stream>>>(Wq, Wk, Wv, Wo, Thi, Tlo);
    prep_tables_kernel<<<1, 256, 0, stream>>>(Wd1, bd1, Wd2, bd2, abPack, lut);
    split_x_kernel<<<dim3(1536), 256, 0, stream>>>(x, xhi, xlo);

    dim3 gGemm(12, 64);
    gemm_mfma_kernel<0><<<gGemm, 256, 0, stream>>>(
        xhi, xlo, Thi + (size_t)0 * 768 * 768, Tlo + (size_t)0 * 768 * 768,
        bq, qhi, qlo);
    gemm_mfma_kernel<0><<<gGemm, 256, 0, stream>>>(
        xhi, xlo, Thi + (size_t)1 * 768 * 768, Tlo + (size_t)1 * 768 * 768,
        bk, khi, klo);
    gemm_mfma_kernel<1><<<gGemm, 256, 0, stream>>>(
        xhi, xlo, Thi + (size_t)2 * 768 * 768, Tlo + (size_t)2 * 768 * 768,
        bv, vThi, vTlo);

    attn_flash_kernel<<<dim3(16, 2, 48), 256, 0, stream>>>(
        qhi, qlo, khi, klo, vThi, vTlo, coords, abPack, lut,
        e_ws, mT, mlh, Hp);

    norm_kernel<<<dim3(6144), 256, 0, stream>>>(e_ws, mT, mlh, attn, wcomb);

    gemm_out_kernel<<<gGemm, 256, 0, stream>>>(
        Hp, Hp + QKV_ELEMS, wcomb,
        Thi + (size_t)3 * 768 * 768, Tlo + (size_t)3 * 768 * 768,
        bo, out_main);
}